// Round 12
// baseline (215.614 us; speedup 1.0000x reference)
//
#include <hip/hip_runtime.h>
#include <stdint.h>

// Problem constants (match reference)
#define N_NODES  50000
#define N_EDGES  800000
#define D        256
#define D_OUT    16
#define N_GRAPHS 128
#define NB_SCAN  196        // 196*256 = 50176 >= N_NODES+1

// JAX jax_threefry_partitionable=True: bits32(i) = fold(threefry2x32((0,42),(0,i))),
// fold = o0 ^ o1; keep iff top bit == 0.  (verified round 2, absmax 0.0)

typedef short bf16x8 __attribute__((ext_vector_type(8)));
typedef float f32x4  __attribute__((ext_vector_type(4)));

__device__ __forceinline__ uint32_t rotl32(uint32_t x, int d) {
    return (x << d) | (x >> (32 - d));
}

__device__ __forceinline__ void threefry2x32(uint32_t k0, uint32_t k1,
                                             uint32_t c0, uint32_t c1,
                                             uint32_t& o0, uint32_t& o1) {
    uint32_t ks2 = k0 ^ k1 ^ 0x1BD11BDAu;
    uint32_t x0 = c0 + k0, x1 = c1 + k1;
    x0 += x1; x1 = rotl32(x1, 13); x1 ^= x0;
    x0 += x1; x1 = rotl32(x1, 15); x1 ^= x0;
    x0 += x1; x1 = rotl32(x1, 26); x1 ^= x0;
    x0 += x1; x1 = rotl32(x1, 6);  x1 ^= x0;
    x0 += k1; x1 += ks2 + 1u;
    x0 += x1; x1 = rotl32(x1, 17); x1 ^= x0;
    x0 += x1; x1 = rotl32(x1, 29); x1 ^= x0;
    x0 += x1; x1 = rotl32(x1, 16); x1 ^= x0;
    x0 += x1; x1 = rotl32(x1, 24); x1 ^= x0;
    x0 += ks2; x1 += k0 + 2u;
    x0 += x1; x1 = rotl32(x1, 13); x1 ^= x0;
    x0 += x1; x1 = rotl32(x1, 15); x1 ^= x0;
    x0 += x1; x1 = rotl32(x1, 26); x1 ^= x0;
    x0 += x1; x1 = rotl32(x1, 6);  x1 ^= x0;
    x0 += k0; x1 += k1 + 3u;
    x0 += x1; x1 = rotl32(x1, 17); x1 ^= x0;
    x0 += x1; x1 = rotl32(x1, 29); x1 ^= x0;
    x0 += x1; x1 = rotl32(x1, 16); x1 ^= x0;
    x0 += x1; x1 = rotl32(x1, 24); x1 ^= x0;
    x0 += k1; x1 += ks2 + 4u;
    x0 += x1; x1 = rotl32(x1, 13); x1 ^= x0;
    x0 += x1; x1 = rotl32(x1, 15); x1 ^= x0;
    x0 += x1; x1 = rotl32(x1, 26); x1 ^= x0;
    x0 += x1; x1 = rotl32(x1, 6);  x1 ^= x0;
    x0 += ks2; x1 += k0 + 5u;
    o0 = x0; o1 = x1;
}

__device__ __forceinline__ bool dropout_keep(uint32_t i) {
    uint32_t o0, o1;
    threefry2x32(0u, 42u, 0u, i, o0, o1);
    return ((o0 ^ o1) & 0x80000000u) == 0u;
}

// pack keep-bits for elements [i0, i0+8) into one byte
__device__ __forceinline__ uint32_t mask_byte(uint32_t i0) {
    uint32_t b = 0;
#pragma unroll
    for (int k = 0; k < 8; k++)
        b |= (dropout_keep(i0 + k) ? 1u : 0u) << k;
    return b;
}

__device__ __forceinline__ uint32_t bf16_rne(float f) {   // fp32 -> bf16 bits (RNE)
    uint32_t u = __float_as_uint(f);
    return (u + 0x7FFFu + ((u >> 16) & 1u)) >> 16;
}

// blocks 0..15: W[k][n] f32 -> wt[n][k] bf16 (transposed, packed)
// blocks 16..: degsum = 0 (f64), sums = 0
__global__ __launch_bounds__(256) void k_init(const float* __restrict__ W,
                                              ushort* __restrict__ wt,
                                              double* degsum, float* sums) {
    int t = threadIdx.x;
    if (blockIdx.x < 16) {
        __shared__ float td[64][65];
        int kb = blockIdx.x & 3, nb = blockIdx.x >> 2;   // 4x4 tiles of 64x64
        int nl = t & 63, r4 = t >> 6;
#pragma unroll
        for (int i = 0; i < 16; i++) {
            int kl = r4 + 4 * i;
            td[kl][nl] = W[(size_t)(kb * 64 + kl) * 256 + nb * 64 + nl];
        }
        __syncthreads();
        int kp = t & 31, nl2 = t >> 5;
        uint32_t* wt32 = (uint32_t*)wt;
#pragma unroll
        for (int i = 0; i < 8; i++) {
            int n = nl2 + 8 * i;
            uint32_t p = bf16_rne(td[2 * kp][n]) | (bf16_rne(td[2 * kp + 1][n]) << 16);
            wt32[((size_t)(nb * 64 + n) * 256 + kb * 64 + 2 * kp) >> 1] = p;
        }
    } else {
        int i = (blockIdx.x - 16) * 256 + t;
        if (i < N_NODES) degsum[i] = 0.0;
        if (i < N_GRAPHS * D) sums[i] = 0.0f;
    }
}

// ONE f64 atomic per edge (count in high bits, sum ew in fraction)
// + dropout-mask bytes for elements [0, 6.4M)  (VALU hides under atomic stalls)
__global__ __launch_bounds__(256) void k_edeg(const int* __restrict__ ei,
                                              const float* __restrict__ ew,
                                              double* __restrict__ degsum,
                                              uint8_t* __restrict__ mask8) {
    int e = blockIdx.x * 256 + threadIdx.x;   // grid is exactly 800000 threads
    int c = ei[N_EDGES + e];
    atomicAdd(&degsum[c], 4294967296.0 + (double)ew[e]);
    mask8[e] = (uint8_t)mask_byte((uint32_t)e * 8u);
}

// scan phase 1: degsum -> dinv + cnt(start[i]); per-block reduce of counts
__global__ __launch_bounds__(256) void k_scan1(const double* __restrict__ degsum,
                                               float* __restrict__ dinv,
                                               int* __restrict__ start,
                                               int* __restrict__ partial) {
    __shared__ int sd[256];
    int t = threadIdx.x;
    int i = blockIdx.x * 256 + t;
    int cnt = 0;
    if (i < N_NODES) {
        double val = degsum[i];
        cnt = (int)(val * (1.0 / 4294967296.0));          // exact
        float deg = (float)(val - (double)cnt * 4294967296.0) + 1.0f;  // +self-loop
        dinv[i] = rsqrtf(deg);                             // deg >= 1 always
        start[i] = cnt;
    }
    sd[t] = cnt;
    __syncthreads();
    for (int d = 128; d > 0; d >>= 1) {
        if (t < d) sd[t] += sd[t + d];
        __syncthreads();
    }
    if (t == 0) partial[blockIdx.x] = sd[0];
}

// scan phase 2+3 fused: every block redundantly scans the 196 partials in LDS,
// then does its own 256-chunk scan + base offset -> start/cursor (coalesced).
__global__ __launch_bounds__(256) void k_scan3(int* __restrict__ start,
                                               int* __restrict__ cursor,
                                               const int* __restrict__ partial) {
    __shared__ int sp[256];
    __shared__ int so[256];
    __shared__ int sd[256];
    int t = threadIdx.x;
    int pv = (t < NB_SCAN) ? partial[t] : 0;
    sp[t] = pv; so[t] = pv;
    __syncthreads();
    for (int d = 1; d < 256; d <<= 1) {
        int u = (t >= d) ? sp[t - d] : 0;
        __syncthreads();
        sp[t] += u;
        __syncthreads();
    }
    int base = sp[blockIdx.x] - so[blockIdx.x];    // exclusive prefix of this block

    int i = blockIdx.x * 256 + t;
    int v = (i < N_NODES) ? start[i] : 0;
    sd[t] = v;
    __syncthreads();
    for (int d = 1; d < 256; d <<= 1) {
        int u = (t >= d) ? sd[t - d] : 0;
        __syncthreads();
        sd[t] += u;
        __syncthreads();
    }
    int val = base + sd[t] - v;                    // exclusive prefix
    if (i < N_NODES) {
        start[i] = val;
        cursor[i] = val;
    } else if (i == N_NODES) {
        start[N_NODES] = val;                      // == grand total
    }
}

// scatter each edge's (row, RAW ew) into its CSR slot
// + dropout-mask bytes for elements [6.4M, 12.8M)
__global__ __launch_bounds__(256) void k_fill(const int* __restrict__ ei,
                                              const float* __restrict__ ew,
                                              int* __restrict__ cursor,
                                              int2* __restrict__ edge,
                                              uint8_t* __restrict__ mask8) {
    int e = blockIdx.x * 256 + threadIdx.x;   // grid is exactly 800000 threads
    int r = ei[e];
    int c = ei[N_EDGES + e];
    int pos = atomicAdd(&cursor[c], 1);
    edge[pos] = make_int2(r, __float_as_int(ew[e]));
    mask8[800000 + e] = (uint8_t)mask_byte(6400000u + (uint32_t)e * 8u);
}

// ---------------- MFMA GEMM: h'(bf16) = dinv[row] * (x @ W1) ---------------
__device__ __forceinline__ int swz(int row, int kByte) {
    return (row << 9) + (kByte ^ ((row & 7) << 4));
}

__global__ __launch_bounds__(256) void k_gemm(const float* __restrict__ x,
                                              const ushort* __restrict__ wt,
                                              const float* __restrict__ dinv,
                                              ushort* __restrict__ hb) {
    __shared__ __align__(16) char smem[65536];   // A: [0,32K), Bt: [32K,64K)
    __shared__ float sdinv[64];
    int tid = threadIdx.x;
    int Mbase = blockIdx.x * 64;

    if (tid < 64) {
        int node = Mbase + tid; if (node >= N_NODES) node = N_NODES - 1;
        sdinv[tid] = dinv[node];
    }
    // ---- stage A: x[Mbase..+63][0..255] -> bf16, swizzled ----
    const float4* xv = (const float4*)x;
#pragma unroll
    for (int i = 0; i < 16; i++) {
        int f = tid + i * 256;        // flat float4 id, 0..4095
        int r = f >> 6;               // row 0..63
        int c4 = f & 63;              // float4 index -> k = 4*c4
        int node = Mbase + r; if (node >= N_NODES) node = N_NODES - 1;
        float4 v = xv[(size_t)node * 64 + c4];
        uint32_t p0 = bf16_rne(v.x) | (bf16_rne(v.y) << 16);
        uint32_t p1 = bf16_rne(v.z) | (bf16_rne(v.w) << 16);
        *(uint2*)(smem + swz(r, c4 * 8)) = make_uint2(p0, p1);
    }

    int l = tid & 63;
    int w = tid >> 6;
    int wr = w >> 1, wc = w & 1;          // wave grid 2x2, each 32x32
    int lr = l & 15;
    int kg = l >> 4;
    int drow = (l >> 4) * 4;
    int dcol = l & 15;
    const uint4* wt4 = (const uint4*)wt;  // 16B units; 32 per 512B row

    for (int nb = 0; nb < 4; nb++) {
        // ---- stage Bt tile: wt rows nb*64..+63 (coalesced uint4 copy) ----
#pragma unroll
        for (int i = 0; i < 8; i++) {
            int f = tid + i * 256;    // 0..2047 uint4
            int r = f >> 5;           // row 0..63
            int c = f & 31;           // 16B chunk
            uint4 v = wt4[(size_t)(nb * 64 + r) * 32 + c];
            *(uint4*)(smem + 32768 + swz(r, c * 16)) = v;
        }
        __syncthreads();

        f32x4 acc00 = {0.f, 0.f, 0.f, 0.f};
        f32x4 acc01 = acc00, acc10 = acc00, acc11 = acc00;
#pragma unroll
        for (int ks = 0; ks < 8; ks++) {
            int kB = ks * 64 + kg * 16;
            bf16x8 a0 = *(const bf16x8*)(smem + swz(wr * 32 + lr, kB));
            bf16x8 a1 = *(const bf16x8*)(smem + swz(wr * 32 + 16 + lr, kB));
            bf16x8 b0 = *(const bf16x8*)(smem + 32768 + swz(wc * 32 + lr, kB));
            bf16x8 b1 = *(const bf16x8*)(smem + 32768 + swz(wc * 32 + 16 + lr, kB));
            acc00 = __builtin_amdgcn_mfma_f32_16x16x32_bf16(a0, b0, acc00, 0, 0, 0);
            acc01 = __builtin_amdgcn_mfma_f32_16x16x32_bf16(a0, b1, acc01, 0, 0, 0);
            acc10 = __builtin_amdgcn_mfma_f32_16x16x32_bf16(a1, b0, acc10, 0, 0, 0);
            acc11 = __builtin_amdgcn_mfma_f32_16x16x32_bf16(a1, b1, acc11, 0, 0, 0);
        }
        // D layout: row=(l>>4)*4+r, col=l&15  (m89-verified); scale by dinv[row]
        int c0 = nb * 64 + wc * 32 + dcol;
#pragma unroll
        for (int r = 0; r < 4; r++) {
            int lr0 = wr * 32 + drow + r;
            int n0 = Mbase + lr0;
            int n1 = n0 + 16;
            float s0 = sdinv[lr0], s1 = sdinv[lr0 + 16];
            if (n0 < N_NODES) {
                hb[(size_t)n0 * 256 + c0]      = (ushort)bf16_rne(acc00[r] * s0);
                hb[(size_t)n0 * 256 + c0 + 16] = (ushort)bf16_rne(acc01[r] * s0);
            }
            if (n1 < N_NODES) {
                hb[(size_t)n1 * 256 + c0]      = (ushort)bf16_rne(acc10[r] * s1);
                hb[(size_t)n1 * 256 + c0 + 16] = (ushort)bf16_rne(acc11[r] * s1);
            }
        }
        __syncthreads();   // Bt reused next iter
    }
}

// CSR aggregate: 2 edges per wave-step (lanes 0-31 edge j, 32-63 edge j+1,
// 16B/lane gathers), then dinv[n]*(sum + h'[n]) + bias, ReLU, dropout via
// precomputed mask byte, block-level LDS pool flush.
__device__ __forceinline__ void fma8(float* a, uint4 u, float w) {
    uint32_t p;
    p = u.x;
    a[0] = fmaf(w, __uint_as_float(p << 16), a[0]);
    a[1] = fmaf(w, __uint_as_float(p & 0xffff0000u), a[1]);
    p = u.y;
    a[2] = fmaf(w, __uint_as_float(p << 16), a[2]);
    a[3] = fmaf(w, __uint_as_float(p & 0xffff0000u), a[3]);
    p = u.z;
    a[4] = fmaf(w, __uint_as_float(p << 16), a[4]);
    a[5] = fmaf(w, __uint_as_float(p & 0xffff0000u), a[5]);
    p = u.w;
    a[6] = fmaf(w, __uint_as_float(p << 16), a[6]);
    a[7] = fmaf(w, __uint_as_float(p & 0xffff0000u), a[7]);
}

__global__ __launch_bounds__(256) void k_agg(const int* __restrict__ start,
                                             const int2* __restrict__ edge,
                                             const ushort* __restrict__ hb,
                                             const float* __restrict__ dinv,
                                             const float* __restrict__ b1,
                                             const int* __restrict__ gidx,
                                             const uint8_t* __restrict__ mask8,
                                             float* __restrict__ sums) {
    __shared__ float ls[4][256];
    int wid = threadIdx.x >> 6;
    int l = threadIdx.x & 63;
    int half = l >> 5;                     // 0: edge j, 1: edge j+1
    int cl = l & 31;                       // 16B column chunk (cols 8cl..8cl+7)
    int n = blockIdx.x * 4 + wid;          // always < N_NODES
    const uint4* h16 = (const uint4*)hb;   // 32 uint4 per 512B row
    int s = start[n], e = start[n + 1];

    float a0[8] = {0,0,0,0,0,0,0,0}, a1[8] = {0,0,0,0,0,0,0,0};
    float a2[8] = {0,0,0,0,0,0,0,0}, a3[8] = {0,0,0,0,0,0,0,0};
    int j = s;
    for (; j + 8 <= e; j += 8) {
        int2 e0 = edge[j + 0 + half];
        int2 e1 = edge[j + 2 + half];
        int2 e2 = edge[j + 4 + half];
        int2 e3 = edge[j + 6 + half];
        uint4 u0 = h16[(size_t)e0.x * 32 + cl];
        uint4 u1 = h16[(size_t)e1.x * 32 + cl];
        uint4 u2 = h16[(size_t)e2.x * 32 + cl];
        uint4 u3 = h16[(size_t)e3.x * 32 + cl];
        fma8(a0, u0, __int_as_float(e0.y));
        fma8(a1, u1, __int_as_float(e1.y));
        fma8(a2, u2, __int_as_float(e2.y));
        fma8(a3, u3, __int_as_float(e3.y));
    }
    for (; j + 2 <= e; j += 2) {
        int2 ee = edge[j + half];
        uint4 u = h16[(size_t)ee.x * 32 + cl];
        fma8(a0, u, __int_as_float(ee.y));
    }
    if (j < e) {                           // odd remainder: half1 contributes 0
        int2 ee = edge[j];
        uint4 u = h16[(size_t)ee.x * 32 + cl];
        float w = half ? 0.0f : __int_as_float(ee.y);
        fma8(a0, u, w);
    }
    float full[8];
#pragma unroll
    for (int k = 0; k < 8; k++)
        full[k] = (a0[k] + a1[k]) + (a2[k] + a3[k]);
#pragma unroll
    for (int k = 0; k < 8; k++)
        full[k] += __shfl_xor(full[k], 32, 64);   // combine the two edge-halves

    // self-loop + bias + relu + dropout for this lane's 4 cols
    float dn = dinv[n];
    uint4 un = h16[(size_t)n * 32 + cl];
    uint32_t q0 = half ? un.z : un.x;
    uint32_t q1 = half ? un.w : un.y;
    float hn0 = __uint_as_float(q0 << 16);
    float hn1 = __uint_as_float(q0 & 0xffff0000u);
    float hn2 = __uint_as_float(q1 << 16);
    float hn3 = __uint_as_float(q1 & 0xffff0000u);
    int off = 4 * half;
    int col = 8 * cl + off;
    float4 bv = ((const float4*)b1)[2 * cl + half];
    float v0 = fmaxf(dn * (full[off + 0] + hn0) + bv.x, 0.f);
    float v1 = fmaxf(dn * (full[off + 1] + hn1) + bv.y, 0.f);
    float v2 = fmaxf(dn * (full[off + 2] + hn2) + bv.z, 0.f);
    float v3 = fmaxf(dn * (full[off + 3] + hn3) + bv.w, 0.f);
    uint32_t mb = mask8[(size_t)n * 32 + cl];
    v0 = (mb & (1u << (off + 0))) ? v0 * 2.f : 0.f;
    v1 = (mb & (1u << (off + 1))) ? v1 * 2.f : 0.f;
    v2 = (mb & (1u << (off + 2))) ? v2 * 2.f : 0.f;
    v3 = (mb & (1u << (off + 3))) ? v3 * 2.f : 0.f;

    int gfirst = gidx[blockIdx.x * 4];
    int glast  = gidx[blockIdx.x * 4 + 3];
    if (gfirst == glast) {                 // block-uniform branch (~99% of blocks)
        *(float4*)&ls[wid][col] = make_float4(v0, v1, v2, v3);
        __syncthreads();
        int t = threadIdx.x;
        float sv = (ls[0][t] + ls[1][t]) + (ls[2][t] + ls[3][t]);
        atomicAdd(&sums[(size_t)gfirst * D + t], sv);
    } else {                               // graph boundary inside block (rare)
        int g = gidx[n];
        float* sg = &sums[(size_t)g * D + col];
        atomicAdd(sg + 0, v0);
        atomicAdd(sg + 1, v1);
        atomicAdd(sg + 2, v2);
        atomicAdd(sg + 3, v3);
    }
}

// pooled = sums/cnt (cnt via binary search on sorted gidx); out = pooled@fcW+fcb
__global__ __launch_bounds__(256) void k_out(const float* __restrict__ sums,
                                             const int* __restrict__ gidx,
                                             const float* __restrict__ fcW,
                                             const float* __restrict__ fcb,
                                             float* __restrict__ out) {
    __shared__ int sh[2];
    __shared__ float p[D];
    int g = blockIdx.x, t = threadIdx.x;
    if (t == 0) {
        int lo = 0, hi = N_NODES;
        while (lo < hi) { int m = (lo + hi) >> 1; if (gidx[m] < g) lo = m + 1; else hi = m; }
        sh[0] = lo;
        int lo2 = lo; hi = N_NODES;
        while (lo2 < hi) { int m = (lo2 + hi) >> 1; if (gidx[m] < g + 1) lo2 = m + 1; else hi = m; }
        sh[1] = lo2;
    }
    __syncthreads();
    float c = fmaxf((float)(sh[1] - sh[0]), 1.0f);
    p[t] = sums[(size_t)g * D + t] / c;
    __syncthreads();
    if (t < D_OUT) {
        float acc = fcb[t];
        for (int k = 0; k < D; k++)
            acc = fmaf(p[k], fcW[k * D_OUT + t], acc);
        out[g * D_OUT + t] = acc;
    }
}

extern "C" void kernel_launch(void* const* d_in, const int* in_sizes, int n_in,
                              void* d_out, int out_size, void* d_ws, size_t ws_size,
                              hipStream_t stream) {
    const float* x   = (const float*)d_in[0];
    const int*   ei  = (const int*)d_in[1];
    const float* ew  = (const float*)d_in[2];
    const int*   gix = (const int*)d_in[3];
    const float* W1  = (const float*)d_in[4];
    const float* b1  = (const float*)d_in[5];
    const float* fcW = (const float*)d_in[6];
    const float* fcb = (const float*)d_in[7];
    float* out = (float*)d_out;

    float*   ws     = (float*)d_ws;
    float*   dinv   = ws;                                  //    65,536 f
    ushort*  hb     = (ushort*)(ws + 65536);               // 12.8M bf16
    int2*    edge   = (int2*)(ws + 65536 + 6400000);       //   800,000 int2
    int*     start  = (int*)(edge + N_EDGES);              //    65,536
    int*     cursor = start + 65536;                       //    65,536
    int*     partial    = cursor + 65536;                  //       256
    ushort*  wt     = (ushort*)(partial + 512);            //    65,536 us
    float*   sums   = (float*)(wt + 65536);                //    32,768 f
    double*  degsum = (double*)(sums + 32768);             //    50,000 f64
    uint8_t* mask8  = (uint8_t*)(degsum + 50048);          // 1,600,000 B
    // total ~36 MB

    k_init<<<NB_SCAN + 16, 256, 0, stream>>>(W1, wt, degsum, sums);
    k_edeg<<<N_EDGES / 256, 256, 0, stream>>>(ei, ew, degsum, mask8);
    k_scan1<<<NB_SCAN, 256, 0, stream>>>(degsum, dinv, start, partial);
    k_scan3<<<NB_SCAN, 256, 0, stream>>>(start, cursor, partial);
    k_fill<<<N_EDGES / 256, 256, 0, stream>>>(ei, ew, cursor, edge, mask8);
    k_gemm<<<(N_NODES + 63) / 64, 256, 0, stream>>>(x, wt, dinv, hb);
    k_agg<<<N_NODES / 4, 256, 0, stream>>>(start, edge, hb, dinv, b1, gix, mask8, sums);
    k_out<<<N_GRAPHS, 256, 0, stream>>>(sums, gix, fcW, fcb, out);
}